// Round 2
// baseline (613.577 us; speedup 1.0000x reference)
//
#include <hip/hip_runtime.h>
#include <hip/hip_bf16.h>
#include <stdint.h>

#define NEG_BIG (-1e24f)

typedef __attribute__((ext_vector_type(8))) short bf16x8;
typedef __attribute__((ext_vector_type(4))) float f32x4;

#define AS1 __attribute__((address_space(1)))
#define AS3 __attribute__((address_space(3)))

__device__ __forceinline__ void gload_lds16(const void* g, void* l) {
    __builtin_amdgcn_global_load_lds((AS1 unsigned*)g, (AS3 unsigned*)l, 16, 0, 0);
}

__device__ __forceinline__ unsigned short f2bf(float f) {
    union { float f; unsigned u; } v; v.f = f;
    return (unsigned short)((v.u + 0x7FFFu + ((v.u >> 16) & 1u)) >> 16);
}

// ---------------------------------------------------------------------------
// K0: detect padding_mask storage dtype from its bit patterns.
// flag: 0 = int32 {0,1}, 1 = uint8 bytes, 2 = float32 {0.0,1.0}
__global__ void detect_mask_kernel(const unsigned* pm, int* flag) {
    __shared__ int notI, notF;
    if (threadIdx.x == 0) { notI = 0; notF = 0; }
    __syncthreads();
    int li = 0, lf = 0;
    for (int i = threadIdx.x; i < 8192; i += 256) {
        unsigned v = pm[i];
        if (v > 1u) li = 1;
        if (v != 0u && v != 0x3F800000u) lf = 1;
    }
    if (li) atomicOr(&notI, 1);
    if (lf) atomicOr(&notF, 1);
    __syncthreads();
    if (threadIdx.x == 0) *flag = notI ? (notF ? 1 : 2) : 0;
}

// ---------------------------------------------------------------------------
// K1 (v2): no-LDS qk + x->bf16. Exact fp32 q/k (score sign thresholds).
// Layout: cg = tid&7 owns d = it*32 + cg*4 .. +4; slot = tid>>3 owns rows
// (r0+slot, r0+32+slot). 64 fp32 partials in regs; shfl_xor(1,2,4) reduce.
__global__ __launch_bounds__(256, 2)
void qk_conv_kernel(const float* __restrict__ x,
                    const float* __restrict__ Wq, const float* __restrict__ bq,
                    const float* __restrict__ Wk, const float* __restrict__ bk,
                    const void* __restrict__ pm, const int* __restrict__ pmflag,
                    unsigned short* __restrict__ xbf,
                    float* __restrict__ qo, float* __restrict__ ko) {
    const int tid = threadIdx.x;
    const int cg = tid & 7;
    const int slot = tid >> 3;
    const int r0 = blockIdx.x * 64;
    const int row0 = r0 + slot;
    const int row1 = r0 + 32 + slot;

    float aq0[16], ak0[16], aq1[16], ak1[16];
#pragma unroll
    for (int j = 0; j < 16; j++) { aq0[j] = 0.f; ak0[j] = 0.f; aq1[j] = 0.f; ak1[j] = 0.f; }

    const float* x0 = x + (size_t)row0 * 1024;
    const float* x1 = x + (size_t)row1 * 1024;
    unsigned short* o0 = xbf + (size_t)row0 * 1024;
    unsigned short* o1 = xbf + (size_t)row1 * 1024;

    for (int it = 0; it < 32; ++it) {
        const int d0 = it * 32 + cg * 4;
        const float4 xa = *(const float4*)(x0 + d0);
        const float4 xb = *(const float4*)(x1 + d0);
        uint2 pa, pb;
        pa.x = (unsigned)f2bf(xa.x) | ((unsigned)f2bf(xa.y) << 16);
        pa.y = (unsigned)f2bf(xa.z) | ((unsigned)f2bf(xa.w) << 16);
        pb.x = (unsigned)f2bf(xb.x) | ((unsigned)f2bf(xb.y) << 16);
        pb.y = (unsigned)f2bf(xb.z) | ((unsigned)f2bf(xb.w) << 16);
        *(uint2*)(o0 + d0) = pa;
        *(uint2*)(o1 + d0) = pb;
        const float xav[4] = { xa.x, xa.y, xa.z, xa.w };
        const float xbv[4] = { xb.x, xb.y, xb.z, xb.w };
#pragma unroll
        for (int dd = 0; dd < 4; ++dd) {
            const float4* wqp = (const float4*)(Wq + (size_t)(d0 + dd) * 16);
            const float4* wkp = (const float4*)(Wk + (size_t)(d0 + dd) * 16);
            float4 wq4[4] = { wqp[0], wqp[1], wqp[2], wqp[3] };
            float4 wk4[4] = { wkp[0], wkp[1], wkp[2], wkp[3] };
            const float* wqf = (const float*)wq4;
            const float* wkf = (const float*)wk4;
            const float a = xav[dd], b = xbv[dd];
#pragma unroll
            for (int j = 0; j < 16; j++) {
                aq0[j] = fmaf(a, wqf[j], aq0[j]);
                ak0[j] = fmaf(a, wkf[j], ak0[j]);
                aq1[j] = fmaf(b, wqf[j], aq1[j]);
                ak1[j] = fmaf(b, wkf[j], ak1[j]);
            }
        }
    }
    // reduce across the 8 cg lanes (lanes cg..cg^7 are adjacent in the wave)
#pragma unroll
    for (int m = 1; m <= 4; m <<= 1) {
#pragma unroll
        for (int j = 0; j < 16; j++) {
            aq0[j] += __shfl_xor(aq0[j], m);
            ak0[j] += __shfl_xor(ak0[j], m);
            aq1[j] += __shfl_xor(aq1[j], m);
            ak1[j] += __shfl_xor(ak1[j], m);
        }
    }
    const int flag = *pmflag;
    bool mk0, mk1;
    if (flag == 1) {
        mk0 = ((const unsigned char*)pm)[row0] != 0;
        mk1 = ((const unsigned char*)pm)[row1] != 0;
    } else {
        mk0 = ((const unsigned*)pm)[row0] != 0;
        mk1 = ((const unsigned*)pm)[row1] != 0;
    }
    // each cg lane stores j = 2*cg, 2*cg+1 (compile-time indices via predication)
#pragma unroll
    for (int c = 0; c < 8; ++c) {
        if (cg == c) {
            const int j = c * 2;
            float2 qv0 = make_float2(aq0[j] + bq[j], aq0[j + 1] + bq[j + 1]);
            float2 qv1 = make_float2(aq1[j] + bq[j], aq1[j + 1] + bq[j + 1]);
            float2 kv0 = mk0 ? make_float2(NEG_BIG, NEG_BIG)
                             : make_float2(ak0[j] + bk[j], ak0[j + 1] + bk[j + 1]);
            float2 kv1 = mk1 ? make_float2(NEG_BIG, NEG_BIG)
                             : make_float2(ak1[j] + bk[j], ak1[j + 1] + bk[j + 1]);
            *(float2*)(qo + (size_t)row0 * 16 + j) = qv0;
            *(float2*)(qo + (size_t)row1 * 16 + j) = qv1;
            *(float2*)(ko + (size_t)row0 * 16 + j) = kv0;
            *(float2*)(ko + (size_t)row1 * 16 + j) = kv1;
        }
    }
}

// ---------------------------------------------------------------------------
// K2: WvT[n][k] = bf16(Wv[k][n])  (B-operand layout for MFMA GEMM)
__global__ void wvt_kernel(const float* __restrict__ Wv, unsigned short* __restrict__ WvT) {
    __shared__ float tile[32][33];
    const int k0 = blockIdx.x * 32, n0 = blockIdx.y * 32;
    const int tid = threadIdx.x;
#pragma unroll
    for (int i = 0; i < 4; i++) {
        int idx = i * 256 + tid;
        int r = idx >> 5, c = idx & 31;
        tile[r][c] = Wv[(size_t)(k0 + r) * 1024 + n0 + c];
    }
    __syncthreads();
#pragma unroll
    for (int i = 0; i < 4; i++) {
        int idx = i * 256 + tid;
        int r = idx >> 5, c = idx & 31;
        WvT[(size_t)(n0 + r) * 1024 + k0 + c] = f2bf(tile[c][r]);
    }
}

// ---------------------------------------------------------------------------
// K3 (v2): v = xbf @ WvT + bv, output DIRECTLY transposed: vT[b][e][s].
// XCD swizzle: XCD c owns m-tiles c*32..c*32+31; for each m-tile the 8
// n-tiles are consecutive in dispatch order (A tile + B stays in that L2).
__global__ __launch_bounds__(256, 2)
void vgemm_kernel(const unsigned short* __restrict__ A,   // [32768][1024] bf16
                  const unsigned short* __restrict__ Bt,  // [1024][1024] bf16 (n-major)
                  const float* __restrict__ bias,
                  unsigned short* __restrict__ vTg) {     // [64][1024][512] bf16
    __shared__ __align__(16) unsigned short smem[17408];  // As(4096)+Bs(4096) | vt(128*136)
    unsigned short* As = smem;
    unsigned short* Bs = smem + 4096;
    const int bid = blockIdx.x;
    const int c = bid & 7;
    const int g = bid >> 3;
    const int mt = c * 32 + (g >> 3);
    const int nt = g & 7;
    const int m0 = mt * 128;
    const int n0 = nt * 128;
    const int tid = threadIdx.x;
    const int lane = tid & 63;
    const int wave = tid >> 6;
    const int wm = (wave & 1) * 64;
    const int wn = (wave >> 1) * 64;
    const int l15 = lane & 15;
    const int quad = lane >> 4;
    const int arow = tid >> 2;
    const int acol = (tid & 3) * 8;
    f32x4 acc[4][4];
#pragma unroll
    for (int i = 0; i < 4; i++)
#pragma unroll
        for (int j = 0; j < 4; j++)
#pragma unroll
            for (int r = 0; r < 4; r++) acc[i][j][r] = 0.f;

    for (int k0 = 0; k0 < 1024; k0 += 32) {
        gload_lds16(A + (size_t)(m0 + arow) * 1024 + k0 + acol, As + tid * 8);
        gload_lds16(A + (size_t)(m0 + 64 + arow) * 1024 + k0 + acol, As + 2048 + tid * 8);
        gload_lds16(Bt + (size_t)(n0 + arow) * 1024 + k0 + acol, Bs + tid * 8);
        gload_lds16(Bt + (size_t)(n0 + 64 + arow) * 1024 + k0 + acol, Bs + 2048 + tid * 8);
        __syncthreads();
        bf16x8 af[4], bfr[4];
#pragma unroll
        for (int i = 0; i < 4; i++) {
            af[i]  = *(const bf16x8*)(As + (wm + i * 16 + l15) * 32 + quad * 8);
            bfr[i] = *(const bf16x8*)(Bs + (wn + i * 16 + l15) * 32 + quad * 8);
        }
#pragma unroll
        for (int i = 0; i < 4; i++)
#pragma unroll
            for (int j = 0; j < 4; j++)
                acc[i][j] = __builtin_amdgcn_mfma_f32_16x16x32_bf16(af[i], bfr[j], acc[i][j], 0, 0, 0);
        __syncthreads();
    }
    // epilogue: bias + transpose through LDS, store vT coalesced
    unsigned short* vt = smem;  // reuse (safe: sync above after last reads)
#pragma unroll
    for (int j = 0; j < 4; j++) {
        const int e_local = wn + j * 16 + l15;
        const float bb = bias[n0 + e_local];
#pragma unroll
        for (int i = 0; i < 4; i++) {
            const int s_base = wm + i * 16 + quad * 4;
            unsigned short h0 = f2bf(acc[i][j][0] + bb);
            unsigned short h1 = f2bf(acc[i][j][1] + bb);
            unsigned short h2 = f2bf(acc[i][j][2] + bb);
            unsigned short h3 = f2bf(acc[i][j][3] + bb);
            uint2 u;
            u.x = (unsigned)h0 | ((unsigned)h1 << 16);
            u.y = (unsigned)h2 | ((unsigned)h3 << 16);
            *(uint2*)(vt + e_local * 136 + s_base) = u;
        }
    }
    __syncthreads();
    const int b = m0 >> 9;
    const int sbase = m0 & 511;
#pragma unroll
    for (int p = 0; p < 8; p++) {
        const int idx = p * 256 + tid;
        const int e = idx >> 4;
        const int s8 = (idx & 15) * 8;
        uint4 val = *(const uint4*)(vt + e * 136 + s8);
        *(uint4*)(vTg + ((size_t)b * 1024 + n0 + e) * 512 + sbase + s8) = val;
    }
}

// ---------------------------------------------------------------------------
// K5a: fp32 scores (q.k*4, causal -1e24) + 2-pass softmax.
// Writes UNNORMALIZED exp(s-M) as bf16 P, plus 1/rowsum fp32.
__global__ __launch_bounds__(256, 2)
void score_kernel(const float* __restrict__ q, const float* __restrict__ k,
                  unsigned short* __restrict__ P, float* __restrict__ isum) {
    __shared__ float Kt[512 * 16];
    __shared__ float Qt[128 * 16];
    __shared__ float redm[2][128];
    __shared__ float reds[2][128];
    __shared__ unsigned short Pt[2][64][132];
    const int tid = threadIdx.x;
    const int b = blockIdx.y;
    const int t0 = blockIdx.x * 128;
    {
        const float4* ks = (const float4*)(k + (size_t)b * 512 * 16);
        float4* kd = (float4*)Kt;
#pragma unroll
        for (int i = 0; i < 8; i++) kd[i * 256 + tid] = ks[i * 256 + tid];
        const float4* qs = (const float4*)(q + ((size_t)b * 512 + t0) * 16);
        float4* qd = (float4*)Qt;
#pragma unroll
        for (int i = 0; i < 2; i++) qd[i * 256 + tid] = qs[i * 256 + tid];
    }
    __syncthreads();
    const int row = tid & 127;
    const int half = tid >> 7;
    const int sbeg = half * 256;
    const int tglob = t0 + row;
    float qr[16];
#pragma unroll
    for (int j = 0; j < 16; j++) qr[j] = Qt[row * 16 + j];

    float m = -INFINITY;
    for (int s = sbeg; s < sbeg + 256; s++) {
        const float* kk = Kt + s * 16;
        float dot = 0.f;
#pragma unroll
        for (int j = 0; j < 16; j++) dot = fmaf(qr[j], kk[j], dot);
        float sc = (s > tglob) ? NEG_BIG : dot * 4.0f;
        m = fmaxf(m, sc);
    }
    redm[half][row] = m;
    __syncthreads();
    const float M = fmaxf(redm[0][row], redm[1][row]);
    float sum = 0.f;
    for (int ph = 0; ph < 4; ph++) {
        const int c0 = sbeg + ph * 64;
        for (int s = c0; s < c0 + 64; s++) {
            const float* kk = Kt + s * 16;
            float dot = 0.f;
#pragma unroll
            for (int j = 0; j < 16; j++) dot = fmaf(qr[j], kk[j], dot);
            float sc = (s > tglob) ? NEG_BIG : dot * 4.0f;
            float p = __expf(sc - M);
            sum += p;
            Pt[half][s - c0][row] = f2bf(p);
        }
        __syncthreads();
#pragma unroll
        for (int i = 0; i < 8; i++) {
            int li = i * 256 + tid;
            int h = li >> 10;
            int r = (li >> 3) & 127;
            int cg = li & 7;
            union { unsigned short u[8]; uint4 v; } tmp;
#pragma unroll
            for (int j = 0; j < 8; j++) tmp.u[j] = Pt[h][cg * 8 + j][r];
            *(uint4*)(P + ((size_t)(b * 512 + t0 + r)) * 512 + h * 256 + ph * 64 + cg * 8) = tmp.v;
        }
        __syncthreads();
    }
    reds[half][row] = sum;
    __syncthreads();
    if (half == 0) {
        float tot = reds[0][row] + reds[1][row];
        isum[(size_t)b * 512 + tglob] = 1.0f / tot;
    }
}

// ---------------------------------------------------------------------------
// K5b: out[b][t][e] = (P[b] @ vT[b]^T)[t][e] * isum[b][t]   (full K=512)
// XCD swizzle: XCD c owns batches c*8..c*8+7; within a batch, n-tiles
// consecutive for each m-tile (P m-tile + vT batch stay in L2).
__global__ __launch_bounds__(256, 2)
void pv_kernel(const unsigned short* __restrict__ P,
               const unsigned short* __restrict__ vT,
               const float* __restrict__ isum,
               float* __restrict__ out) {
    __shared__ unsigned short As[128 * 32];
    __shared__ unsigned short Bs[128 * 32];
    const int bid = blockIdx.x;
    const int c = bid & 7;
    const int g = bid >> 3;
    const int b = c * 8 + (g >> 5);
    const int rem = g & 31;
    const int m0 = (rem >> 3) * 128;
    const int n0 = (rem & 7) * 128;
    const int tid = threadIdx.x;
    const int lane = tid & 63;
    const int wave = tid >> 6;
    const int wm = (wave & 1) * 64;
    const int wn = (wave >> 1) * 64;
    const int l15 = lane & 15;
    const int quad = lane >> 4;
    const int arow = tid >> 2;
    const int acol = (tid & 3) * 8;
    const unsigned short* Ab = P + (size_t)b * 512 * 512;
    const unsigned short* Bb = vT + (size_t)b * 1024 * 512;
    f32x4 acc[4][4];
#pragma unroll
    for (int i = 0; i < 4; i++)
#pragma unroll
        for (int j = 0; j < 4; j++)
#pragma unroll
            for (int r = 0; r < 4; r++) acc[i][j][r] = 0.f;

    for (int k0 = 0; k0 < 512; k0 += 32) {
        gload_lds16(Ab + (size_t)(m0 + arow) * 512 + k0 + acol, As + tid * 8);
        gload_lds16(Ab + (size_t)(m0 + 64 + arow) * 512 + k0 + acol, As + 2048 + tid * 8);
        gload_lds16(Bb + (size_t)(n0 + arow) * 512 + k0 + acol, Bs + tid * 8);
        gload_lds16(Bb + (size_t)(n0 + 64 + arow) * 512 + k0 + acol, Bs + 2048 + tid * 8);
        __syncthreads();
        bf16x8 af[4], bfr[4];
#pragma unroll
        for (int i = 0; i < 4; i++) {
            af[i]  = *(const bf16x8*)(As + (wm + i * 16 + l15) * 32 + quad * 8);
            bfr[i] = *(const bf16x8*)(Bs + (wn + i * 16 + l15) * 32 + quad * 8);
        }
#pragma unroll
        for (int i = 0; i < 4; i++)
#pragma unroll
            for (int j = 0; j < 4; j++)
                acc[i][j] = __builtin_amdgcn_mfma_f32_16x16x32_bf16(af[i], bfr[j], acc[i][j], 0, 0, 0);
        __syncthreads();
    }
#pragma unroll
    for (int i = 0; i < 4; i++) {
#pragma unroll
        for (int r = 0; r < 4; r++) {
            const int trow = m0 + wm + i * 16 + quad * 4 + r;
            const float sc = isum[(size_t)b * 512 + trow];
#pragma unroll
            for (int j = 0; j < 4; j++) {
                const int ncol = n0 + wn + j * 16 + l15;
                out[((size_t)b * 512 + trow) * 1024 + ncol] = acc[i][j][r] * sc;
            }
        }
    }
}

// ---------------------------------------------------------------------------
extern "C" void kernel_launch(void* const* d_in, const int* in_sizes, int n_in,
                              void* d_out, int out_size, void* d_ws, size_t ws_size,
                              hipStream_t stream) {
    const float* x  = (const float*)d_in[0];
    const void*  pm = d_in[1];
    const float* Wq = (const float*)d_in[2];
    const float* bq = (const float*)d_in[3];
    const float* Wk = (const float*)d_in[4];
    const float* bk = (const float*)d_in[5];
    const float* Wv = (const float*)d_in[6];
    const float* bv = (const float*)d_in[7];
    float* out = (float*)d_out;

    char* ws = (char*)d_ws;
    const size_t MB = 1024 * 1024;
    unsigned short* xbf = (unsigned short*)ws;                 // 64MB (K1->K3)
    unsigned short* Pun = (unsigned short*)ws;                 // 32MB overlay (K5a->K5b, after xbf dead)
    unsigned short* vT  = (unsigned short*)(ws + 64 * MB);     // 64MB
    float* qbuf = (float*)(ws + 128 * MB);                     // 2MB
    float* kbuf = (float*)(ws + 130 * MB);                     // 2MB
    unsigned short* WvT = (unsigned short*)(ws + 132 * MB);    // 2MB
    float* isum = (float*)(ws + 134 * MB);                     // 128KB
    int* flag   = (int*)(ws + 135 * MB);

    detect_mask_kernel<<<1, 256, 0, stream>>>((const unsigned*)pm, flag);
    qk_conv_kernel<<<512, 256, 0, stream>>>(x, Wq, bq, Wk, bk, pm, flag, xbf, qbuf, kbuf);
    wvt_kernel<<<dim3(32, 32), 256, 0, stream>>>(Wv, WvT);
    vgemm_kernel<<<2048, 256, 0, stream>>>(xbf, WvT, bv, vT);
    score_kernel<<<dim3(4, 64), 256, 0, stream>>>(qbuf, kbuf, Pun, isum);
    pv_kernel<<<2048, 256, 0, stream>>>(Pun, vT, isum, out);
}

// Round 3
// 551.293 us; speedup vs baseline: 1.1130x; 1.1130x over previous
//
#include <hip/hip_runtime.h>
#include <hip/hip_bf16.h>
#include <stdint.h>

#define NEG_BIG (-1e24f)

typedef __attribute__((ext_vector_type(8))) short bf16x8;
typedef __attribute__((ext_vector_type(4))) float f32x4;

#define AS1 __attribute__((address_space(1)))
#define AS3 __attribute__((address_space(3)))

__device__ __forceinline__ void gload_lds16(const void* g, void* l) {
    __builtin_amdgcn_global_load_lds((AS1 unsigned*)g, (AS3 unsigned*)l, 16, 0, 0);
}

__device__ __forceinline__ unsigned short f2bf(float f) {
    union { float f; unsigned u; } v; v.f = f;
    return (unsigned short)((v.u + 0x7FFFu + ((v.u >> 16) & 1u)) >> 16);
}

// ---------------------------------------------------------------------------
// K0: detect padding_mask storage dtype from its bit patterns.
// flag: 0 = int32 {0,1}, 1 = uint8 bytes, 2 = float32 {0.0,1.0}
__global__ void detect_mask_kernel(const unsigned* pm, int* flag) {
    __shared__ int notI, notF;
    if (threadIdx.x == 0) { notI = 0; notF = 0; }
    __syncthreads();
    int li = 0, lf = 0;
    for (int i = threadIdx.x; i < 8192; i += 256) {
        unsigned v = pm[i];
        if (v > 1u) li = 1;
        if (v != 0u && v != 0x3F800000u) lf = 1;
    }
    if (li) atomicOr(&notI, 1);
    if (lf) atomicOr(&notF, 1);
    __syncthreads();
    if (threadIdx.x == 0) *flag = notI ? (notF ? 1 : 2) : 0;
}

// ---------------------------------------------------------------------------
// K1 (v3): LDS-staged x (odd stride -> conflict-free), wave-uniform SGPR
// weights, fused x->bf16. Exact fp32 q/k (score sign thresholds).
// Block: 256 thr / 4 waves, 64 rows. Wave w computes 8 outputs:
//   w0: q[0:8)  w1: q[8:16)  w2: k[0:8)  w3: k[8:16)
// Lane = row. Per d: 1 ds_read_b32 (bank (lane+d)%32, 2-way=free) + 8 fma.
__global__ __launch_bounds__(256, 4)
void qk_conv_kernel(const float* __restrict__ x,
                    const float* __restrict__ Wq, const float* __restrict__ bq,
                    const float* __restrict__ Wk, const float* __restrict__ bk,
                    const void* __restrict__ pm, const int* __restrict__ pmflag,
                    unsigned short* __restrict__ xbf,
                    float* __restrict__ qo, float* __restrict__ ko) {
    __shared__ float xs[64 * 65];
    const int tid = threadIdx.x;
    const int r0 = blockIdx.x * 64;
    const int lane = tid & 63;
    const int wsel = __builtin_amdgcn_readfirstlane(tid >> 6);
    const int jb = (wsel & 1) * 8;
    const float* __restrict__ W = (wsel < 2) ? Wq : Wk;

    const int sr_base = tid >> 4;          // staging row (passes add +16)
    const int sd = (tid & 15) * 4;         // staging d within chunk

    float acc[8];
#pragma unroll
    for (int j = 0; j < 8; j++) acc[j] = 0.f;

    for (int c0 = 0; c0 < 1024; c0 += 64) {
        // ---- stage x[r0..r0+64)[c0..c0+64) into LDS; fused bf16 convert
#pragma unroll
        for (int p = 0; p < 4; p++) {
            const int sr = sr_base + p * 16;
            const float4 xv = *(const float4*)(x + (size_t)(r0 + sr) * 1024 + c0 + sd);
            uint2 pk;
            pk.x = (unsigned)f2bf(xv.x) | ((unsigned)f2bf(xv.y) << 16);
            pk.y = (unsigned)f2bf(xv.z) | ((unsigned)f2bf(xv.w) << 16);
            *(uint2*)(xbf + (size_t)(r0 + sr) * 1024 + c0 + sd) = pk;
            xs[sr * 65 + sd + 0] = xv.x;
            xs[sr * 65 + sd + 1] = xv.y;
            xs[sr * 65 + sd + 2] = xv.z;
            xs[sr * 65 + sd + 3] = xv.w;
        }
        __syncthreads();
        // ---- accumulate: per d, uniform 8-float weight row (SGPR), 8 fma
#pragma unroll 4
        for (int d = 0; d < 64; d++) {
            const int du = c0 + d;
            const float* __restrict__ w = W + (size_t)du * 16 + jb;
            const float xv = xs[lane * 65 + d];
#pragma unroll
            for (int j = 0; j < 8; j++) acc[j] = fmaf(xv, w[j], acc[j]);
        }
        __syncthreads();
    }

    // ---- epilogue: bias (+ mask for k-waves), store 8 floats per thread
    const int grow = r0 + lane;
    if (wsel < 2) {
        float4 a, b2;
        a.x = acc[0] + bq[jb + 0]; a.y = acc[1] + bq[jb + 1];
        a.z = acc[2] + bq[jb + 2]; a.w = acc[3] + bq[jb + 3];
        b2.x = acc[4] + bq[jb + 4]; b2.y = acc[5] + bq[jb + 5];
        b2.z = acc[6] + bq[jb + 6]; b2.w = acc[7] + bq[jb + 7];
        *(float4*)(qo + (size_t)grow * 16 + jb) = a;
        *(float4*)(qo + (size_t)grow * 16 + jb + 4) = b2;
    } else {
        const int flag = *pmflag;
        bool mk;
        if (flag == 1) mk = ((const unsigned char*)pm)[grow] != 0;
        else           mk = ((const unsigned*)pm)[grow] != 0;
        float4 a, b2;
        if (mk) {
            a.x = a.y = a.z = a.w = NEG_BIG;
            b2 = a;
        } else {
            a.x = acc[0] + bk[jb + 0]; a.y = acc[1] + bk[jb + 1];
            a.z = acc[2] + bk[jb + 2]; a.w = acc[3] + bk[jb + 3];
            b2.x = acc[4] + bk[jb + 4]; b2.y = acc[5] + bk[jb + 5];
            b2.z = acc[6] + bk[jb + 6]; b2.w = acc[7] + bk[jb + 7];
        }
        *(float4*)(ko + (size_t)grow * 16 + jb) = a;
        *(float4*)(ko + (size_t)grow * 16 + jb + 4) = b2;
    }
}

// ---------------------------------------------------------------------------
// K2: WvT[n][k] = bf16(Wv[k][n])  (B-operand layout for MFMA GEMM)
__global__ void wvt_kernel(const float* __restrict__ Wv, unsigned short* __restrict__ WvT) {
    __shared__ float tile[32][33];
    const int k0 = blockIdx.x * 32, n0 = blockIdx.y * 32;
    const int tid = threadIdx.x;
#pragma unroll
    for (int i = 0; i < 4; i++) {
        int idx = i * 256 + tid;
        int r = idx >> 5, c = idx & 31;
        tile[r][c] = Wv[(size_t)(k0 + r) * 1024 + n0 + c];
    }
    __syncthreads();
#pragma unroll
    for (int i = 0; i < 4; i++) {
        int idx = i * 256 + tid;
        int r = idx >> 5, c = idx & 31;
        WvT[(size_t)(n0 + r) * 1024 + k0 + c] = f2bf(tile[c][r]);
    }
}

// ---------------------------------------------------------------------------
// K3: v = xbf @ WvT + bv, output DIRECTLY transposed: vT[b][e][s].
// XCD swizzle: XCD c owns m-tiles c*32..c*32+31; for each m-tile the 8
// n-tiles are consecutive in dispatch order (A tile + B stays in that L2).
__global__ __launch_bounds__(256, 2)
void vgemm_kernel(const unsigned short* __restrict__ A,   // [32768][1024] bf16
                  const unsigned short* __restrict__ Bt,  // [1024][1024] bf16 (n-major)
                  const float* __restrict__ bias,
                  unsigned short* __restrict__ vTg) {     // [64][1024][512] bf16
    __shared__ __align__(16) unsigned short smem[17408];  // As(4096)+Bs(4096) | vt(128*136)
    unsigned short* As = smem;
    unsigned short* Bs = smem + 4096;
    const int bid = blockIdx.x;
    const int c = bid & 7;
    const int g = bid >> 3;
    const int mt = c * 32 + (g >> 3);
    const int nt = g & 7;
    const int m0 = mt * 128;
    const int n0 = nt * 128;
    const int tid = threadIdx.x;
    const int lane = tid & 63;
    const int wave = tid >> 6;
    const int wm = (wave & 1) * 64;
    const int wn = (wave >> 1) * 64;
    const int l15 = lane & 15;
    const int quad = lane >> 4;
    const int arow = tid >> 2;
    const int acol = (tid & 3) * 8;
    f32x4 acc[4][4];
#pragma unroll
    for (int i = 0; i < 4; i++)
#pragma unroll
        for (int j = 0; j < 4; j++)
#pragma unroll
            for (int r = 0; r < 4; r++) acc[i][j][r] = 0.f;

    for (int k0 = 0; k0 < 1024; k0 += 32) {
        gload_lds16(A + (size_t)(m0 + arow) * 1024 + k0 + acol, As + tid * 8);
        gload_lds16(A + (size_t)(m0 + 64 + arow) * 1024 + k0 + acol, As + 2048 + tid * 8);
        gload_lds16(Bt + (size_t)(n0 + arow) * 1024 + k0 + acol, Bs + tid * 8);
        gload_lds16(Bt + (size_t)(n0 + 64 + arow) * 1024 + k0 + acol, Bs + 2048 + tid * 8);
        __syncthreads();
        bf16x8 af[4], bfr[4];
#pragma unroll
        for (int i = 0; i < 4; i++) {
            af[i]  = *(const bf16x8*)(As + (wm + i * 16 + l15) * 32 + quad * 8);
            bfr[i] = *(const bf16x8*)(Bs + (wn + i * 16 + l15) * 32 + quad * 8);
        }
#pragma unroll
        for (int i = 0; i < 4; i++)
#pragma unroll
            for (int j = 0; j < 4; j++)
                acc[i][j] = __builtin_amdgcn_mfma_f32_16x16x32_bf16(af[i], bfr[j], acc[i][j], 0, 0, 0);
        __syncthreads();
    }
    // epilogue: bias + transpose through LDS, store vT coalesced
    unsigned short* vt = smem;  // reuse (safe: sync above after last reads)
#pragma unroll
    for (int j = 0; j < 4; j++) {
        const int e_local = wn + j * 16 + l15;
        const float bb = bias[n0 + e_local];
#pragma unroll
        for (int i = 0; i < 4; i++) {
            const int s_base = wm + i * 16 + quad * 4;
            unsigned short h0 = f2bf(acc[i][j][0] + bb);
            unsigned short h1 = f2bf(acc[i][j][1] + bb);
            unsigned short h2 = f2bf(acc[i][j][2] + bb);
            unsigned short h3 = f2bf(acc[i][j][3] + bb);
            uint2 u;
            u.x = (unsigned)h0 | ((unsigned)h1 << 16);
            u.y = (unsigned)h2 | ((unsigned)h3 << 16);
            *(uint2*)(vt + e_local * 136 + s_base) = u;
        }
    }
    __syncthreads();
    const int b = m0 >> 9;
    const int sbase = m0 & 511;
#pragma unroll
    for (int p = 0; p < 8; p++) {
        const int idx = p * 256 + tid;
        const int e = idx >> 4;
        const int s8 = (idx & 15) * 8;
        uint4 val = *(const uint4*)(vt + e * 136 + s8);
        *(uint4*)(vTg + ((size_t)b * 1024 + n0 + e) * 512 + sbase + s8) = val;
    }
}

// ---------------------------------------------------------------------------
// K5a: fp32 scores (q.k*4, causal -1e24) + 2-pass softmax.
// Writes UNNORMALIZED exp(s-M) as bf16 P, plus 1/rowsum fp32.
__global__ __launch_bounds__(256, 2)
void score_kernel(const float* __restrict__ q, const float* __restrict__ k,
                  unsigned short* __restrict__ P, float* __restrict__ isum) {
    __shared__ float Kt[512 * 16];
    __shared__ float Qt[128 * 16];
    __shared__ float redm[2][128];
    __shared__ float reds[2][128];
    __shared__ unsigned short Pt[2][64][132];
    const int tid = threadIdx.x;
    const int b = blockIdx.y;
    const int t0 = blockIdx.x * 128;
    {
        const float4* ks = (const float4*)(k + (size_t)b * 512 * 16);
        float4* kd = (float4*)Kt;
#pragma unroll
        for (int i = 0; i < 8; i++) kd[i * 256 + tid] = ks[i * 256 + tid];
        const float4* qs = (const float4*)(q + ((size_t)b * 512 + t0) * 16);
        float4* qd = (float4*)Qt;
#pragma unroll
        for (int i = 0; i < 2; i++) qd[i * 256 + tid] = qs[i * 256 + tid];
    }
    __syncthreads();
    const int row = tid & 127;
    const int half = tid >> 7;
    const int sbeg = half * 256;
    const int tglob = t0 + row;
    float qr[16];
#pragma unroll
    for (int j = 0; j < 16; j++) qr[j] = Qt[row * 16 + j];

    float m = -INFINITY;
    for (int s = sbeg; s < sbeg + 256; s++) {
        const float* kk = Kt + s * 16;
        float dot = 0.f;
#pragma unroll
        for (int j = 0; j < 16; j++) dot = fmaf(qr[j], kk[j], dot);
        float sc = (s > tglob) ? NEG_BIG : dot * 4.0f;
        m = fmaxf(m, sc);
    }
    redm[half][row] = m;
    __syncthreads();
    const float M = fmaxf(redm[0][row], redm[1][row]);
    float sum = 0.f;
    for (int ph = 0; ph < 4; ph++) {
        const int c0 = sbeg + ph * 64;
        for (int s = c0; s < c0 + 64; s++) {
            const float* kk = Kt + s * 16;
            float dot = 0.f;
#pragma unroll
            for (int j = 0; j < 16; j++) dot = fmaf(qr[j], kk[j], dot);
            float sc = (s > tglob) ? NEG_BIG : dot * 4.0f;
            float p = __expf(sc - M);
            sum += p;
            Pt[half][s - c0][row] = f2bf(p);
        }
        __syncthreads();
#pragma unroll
        for (int i = 0; i < 8; i++) {
            int li = i * 256 + tid;
            int h = li >> 10;
            int r = (li >> 3) & 127;
            int cg = li & 7;
            union { unsigned short u[8]; uint4 v; } tmp;
#pragma unroll
            for (int j = 0; j < 8; j++) tmp.u[j] = Pt[h][cg * 8 + j][r];
            *(uint4*)(P + ((size_t)(b * 512 + t0 + r)) * 512 + h * 256 + ph * 64 + cg * 8) = tmp.v;
        }
        __syncthreads();
    }
    reds[half][row] = sum;
    __syncthreads();
    if (half == 0) {
        float tot = reds[0][row] + reds[1][row];
        isum[(size_t)b * 512 + tglob] = 1.0f / tot;
    }
}

// ---------------------------------------------------------------------------
// K5b: out[b][t][e] = (P[b] @ vT[b]^T)[t][e] * isum[b][t]   (full K=512)
// XCD swizzle: XCD c owns batches c*8..c*8+7; within a batch, n-tiles
// consecutive for each m-tile (P m-tile + vT batch stay in L2).
__global__ __launch_bounds__(256, 2)
void pv_kernel(const unsigned short* __restrict__ P,
               const unsigned short* __restrict__ vT,
               const float* __restrict__ isum,
               float* __restrict__ out) {
    __shared__ unsigned short As[128 * 32];
    __shared__ unsigned short Bs[128 * 32];
    const int bid = blockIdx.x;
    const int c = bid & 7;
    const int g = bid >> 3;
    const int b = c * 8 + (g >> 5);
    const int rem = g & 31;
    const int m0 = (rem >> 3) * 128;
    const int n0 = (rem & 7) * 128;
    const int tid = threadIdx.x;
    const int lane = tid & 63;
    const int wave = tid >> 6;
    const int wm = (wave & 1) * 64;
    const int wn = (wave >> 1) * 64;
    const int l15 = lane & 15;
    const int quad = lane >> 4;
    const int arow = tid >> 2;
    const int acol = (tid & 3) * 8;
    const unsigned short* Ab = P + (size_t)b * 512 * 512;
    const unsigned short* Bb = vT + (size_t)b * 1024 * 512;
    f32x4 acc[4][4];
#pragma unroll
    for (int i = 0; i < 4; i++)
#pragma unroll
        for (int j = 0; j < 4; j++)
#pragma unroll
            for (int r = 0; r < 4; r++) acc[i][j][r] = 0.f;

    for (int k0 = 0; k0 < 512; k0 += 32) {
        gload_lds16(Ab + (size_t)(m0 + arow) * 512 + k0 + acol, As + tid * 8);
        gload_lds16(Ab + (size_t)(m0 + 64 + arow) * 512 + k0 + acol, As + 2048 + tid * 8);
        gload_lds16(Bb + (size_t)(n0 + arow) * 512 + k0 + acol, Bs + tid * 8);
        gload_lds16(Bb + (size_t)(n0 + 64 + arow) * 512 + k0 + acol, Bs + 2048 + tid * 8);
        __syncthreads();
        bf16x8 af[4], bfr[4];
#pragma unroll
        for (int i = 0; i < 4; i++) {
            af[i]  = *(const bf16x8*)(As + (wm + i * 16 + l15) * 32 + quad * 8);
            bfr[i] = *(const bf16x8*)(Bs + (wn + i * 16 + l15) * 32 + quad * 8);
        }
#pragma unroll
        for (int i = 0; i < 4; i++)
#pragma unroll
            for (int j = 0; j < 4; j++)
                acc[i][j] = __builtin_amdgcn_mfma_f32_16x16x32_bf16(af[i], bfr[j], acc[i][j], 0, 0, 0);
        __syncthreads();
    }
#pragma unroll
    for (int i = 0; i < 4; i++) {
#pragma unroll
        for (int r = 0; r < 4; r++) {
            const int trow = m0 + wm + i * 16 + quad * 4 + r;
            const float sc = isum[(size_t)b * 512 + trow];
#pragma unroll
            for (int j = 0; j < 4; j++) {
                const int ncol = n0 + wn + j * 16 + l15;
                out[((size_t)b * 512 + trow) * 1024 + ncol] = acc[i][j][r] * sc;
            }
        }
    }
}

// ---------------------------------------------------------------------------
extern "C" void kernel_launch(void* const* d_in, const int* in_sizes, int n_in,
                              void* d_out, int out_size, void* d_ws, size_t ws_size,
                              hipStream_t stream) {
    const float* x  = (const float*)d_in[0];
    const void*  pm = d_in[1];
    const float* Wq = (const float*)d_in[2];
    const float* bq = (const float*)d_in[3];
    const float* Wk = (const float*)d_in[4];
    const float* bk = (const float*)d_in[5];
    const float* Wv = (const float*)d_in[6];
    const float* bv = (const float*)d_in[7];
    float* out = (float*)d_out;

    char* ws = (char*)d_ws;
    const size_t MB = 1024 * 1024;
    unsigned short* xbf = (unsigned short*)ws;                 // 64MB (K1->K3)
    unsigned short* Pun = (unsigned short*)ws;                 // 32MB overlay (K5a->K5b, after xbf dead)
    unsigned short* vT  = (unsigned short*)(ws + 64 * MB);     // 64MB
    float* qbuf = (float*)(ws + 128 * MB);                     // 2MB
    float* kbuf = (float*)(ws + 130 * MB);                     // 2MB
    unsigned short* WvT = (unsigned short*)(ws + 132 * MB);    // 2MB
    float* isum = (float*)(ws + 134 * MB);                     // 128KB
    int* flag   = (int*)(ws + 135 * MB);

    detect_mask_kernel<<<1, 256, 0, stream>>>((const unsigned*)pm, flag);
    qk_conv_kernel<<<512, 256, 0, stream>>>(x, Wq, bq, Wk, bk, pm, flag, xbf, qbuf, kbuf);
    wvt_kernel<<<dim3(32, 32), 256, 0, stream>>>(Wv, WvT);
    vgemm_kernel<<<2048, 256, 0, stream>>>(xbf, WvT, bv, vT);
    score_kernel<<<dim3(4, 64), 256, 0, stream>>>(qbuf, kbuf, Pun, isum);
    pv_kernel<<<2048, 256, 0, stream>>>(Pun, vT, isum, out);
}